// Round 11
// baseline (2998.702 us; speedup 1.0000x reference)
//
#include <hip/hip_runtime.h>
#include <hip/hip_bf16.h>

#define H 128
#define H_IN 3
#define TILE 128
#define NTHREADS 512
#define NWAVES (NTHREADS / 64)
#define CPW (H / NWAVES)        // cols per wave = 16
#define NHID 9                  // extra hidden layers
#define NFIN 2                  // final layers

// ---------------------------------------------------------------------------
// Segment index normalization: reference produces int64 bounds, but JAX may
// ship them as int32 (x64 disabled) or int64 (x64 enabled). Detect on device:
// raw word[1] is ends[0] (>=1) for int32, hi(starts[0]) == 0 for int64.
// Writes canonical int32 [B*2] arrays into workspace.
// ---------------------------------------------------------------------------
__global__ void normalize_idx(const int* __restrict__ rawP, const int* __restrict__ rawQ,
                              int* __restrict__ outP, int* __restrict__ outQ, int n) {
    int i = blockIdx.x * blockDim.x + threadIdx.x;
    if (i < n) {
        bool p64 = (rawP[1] == 0);
        bool q64 = (rawQ[1] == 0);
        outP[i] = p64 ? rawP[2 * i] : rawP[i];
        outQ[i] = q64 ? rawQ[2 * i] : rawQ[i];
    }
}

// ---------------------------------------------------------------------------
// find segment s such that idx[s].start <= r < idx[s].end
// (largest s with start_s <= r; correct across empty segments)
// ---------------------------------------------------------------------------
__device__ __forceinline__ int find_seg(const int* __restrict__ idx, int B, int r) {
    int lo = 0, hi = B - 1;
    while (lo < hi) {
        int mid = (lo + hi + 1) >> 1;
        if (idx[2 * mid] <= r) lo = mid; else hi = mid - 1;
    }
    return lo;
}

// ---------------------------------------------------------------------------
// transpose weights into workspace: w0t[k][c] = hW0[c][k], hWt[l][k][c] = hW[l][c][k]
// ---------------------------------------------------------------------------
__global__ void transpose_weights(const float* __restrict__ hW0, const float* __restrict__ hW,
                                  float* __restrict__ w0t, float* __restrict__ hWt,
                                  int n0, int nh) {
    int i = blockIdx.x * blockDim.x + threadIdx.x;
    if (i < n0) {                       // n0 = H_IN * H
        int k = i >> 7, c = i & (H - 1);
        w0t[i] = hW0[c * H_IN + k];
    } else if (i < n0 + nh) {           // nh = NHID * H * H
        int j = i - n0;
        int l = j >> 14, rem = j & 16383, k = rem >> 7, c = rem & (H - 1);
        hWt[j] = hW[l * H * H + c * H + k];
    }
}

// ---------------------------------------------------------------------------
// fused 10-layer MLP + segment-sum. One block = 128 rows.
// xt[k][r] layout (feature-major) so dot-product reads are contiguous.
// Mapping: wave w owns cols [w*16, w*16+16); lane owns rows lane*2, lane*2+1.
// W addresses per k-step are wave-uniform -> scalar (SMEM) loads; FMA reads W
// from SGPR, keeping the VALU issue stream ~pure FMA.
// ---------------------------------------------------------------------------
__global__ __launch_bounds__(NTHREADS, 4)
void mlp_seg_kernel(const float* __restrict__ X, const int* __restrict__ idx, int B,
                    const float* __restrict__ w0t, const float* __restrict__ hb0,
                    const float* __restrict__ hWt, const float* __restrict__ hb,
                    float* __restrict__ seg_out, int N)
{
    __shared__ __align__(16) float xt[H * TILE];   // 64 KB: xt[feature][row]
    __shared__ int s_uni;

    const int tid  = threadIdx.x;
    const int lane = tid & 63;
    const int wid  = __builtin_amdgcn_readfirstlane(tid >> 6);  // wave-uniform scalar
    const int wc0  = wid * CPW;                                 // this wave's col base
    const int base = blockIdx.x * TILE;
    const int r0   = lane * 2;                                  // this lane's row pair

    if (tid == 0) {
        int last = base + TILE - 1;
        if (last >= N) s_uni = -1;     // tail block -> slow path
        else {
            int sa = find_seg(idx, B, base);
            int sb = find_seg(idx, B, last);
            s_uni = (sa == sb) ? sa : -1;
        }
    }

    float acc[2][CPW];

    // ---- layer 0: [N,3] -> 128 features ----
    {
        float xin[2][H_IN];
        #pragma unroll
        for (int j = 0; j < 2; ++j) {
            int gr = base + r0 + j;
            #pragma unroll
            for (int k = 0; k < H_IN; ++k)
                xin[j][k] = (gr < N) ? X[gr * H_IN + k] : 0.f;
        }
        #pragma unroll
        for (int i = 0; i < CPW; ++i) {
            float b = hb0[wc0 + i];
            acc[0][i] = b; acc[1][i] = b;
        }
        #pragma unroll
        for (int k = 0; k < H_IN; ++k) {
            #pragma unroll
            for (int i = 0; i < CPW; ++i) {
                float w = w0t[k * H + wc0 + i];     // uniform
                acc[0][i] = fmaf(xin[0][k], w, acc[0][i]);
                acc[1][i] = fmaf(xin[1][k], w, acc[1][i]);
            }
        }
        #pragma unroll
        for (int i = 0; i < CPW; ++i) {
            float2 v = make_float2(fmaxf(acc[0][i], 0.f), fmaxf(acc[1][i], 0.f));
            *(float2*)&xt[(wc0 + i) * TILE + r0] = v;
        }
    }
    __syncthreads();

    // ---- 9 hidden layers: y[r][c] = relu(b[c] + sum_k W^T[k][c] * x[r][k]) ----
    for (int l = 0; l < NHID; ++l) {
        const float* __restrict__ W = hWt + l * H * H;   // W[k][c]
        #pragma unroll
        for (int i = 0; i < CPW; ++i) {
            float b = hb[l * H + wc0 + i];
            acc[0][i] = b; acc[1][i] = b;
        }
        #pragma unroll 4
        for (int k = 0; k < H; ++k) {
            const float2 xv = *(const float2*)&xt[k * TILE + r0];
            const float* __restrict__ Wk = W + (k << 7) + wc0;   // wave-uniform addr
            #pragma unroll
            for (int i = 0; i < CPW; ++i) {
                float w = Wk[i];
                acc[0][i] = fmaf(xv.x, w, acc[0][i]);
                acc[1][i] = fmaf(xv.y, w, acc[1][i]);
            }
        }
        #pragma unroll
        for (int i = 0; i < CPW; ++i) {
            acc[0][i] = fmaxf(acc[0][i], 0.f);
            acc[1][i] = fmaxf(acc[1][i], 0.f);
        }
        if (l < NHID - 1) {
            __syncthreads();   // all reads of xt done before overwrite
            #pragma unroll
            for (int i = 0; i < CPW; ++i)
                *(float2*)&xt[(wc0 + i) * TILE + r0] = make_float2(acc[0][i], acc[1][i]);
            __syncthreads();
        }
        // last layer: keep relu'd activations in registers for segment reduction
    }

    // ---- fused segment sum ----
    int su = s_uni;
    if (su >= 0) {
        // whole block in one segment: each wave holds all 128 rows for its 16 cols
        #pragma unroll
        for (int i = 0; i < CPW; ++i) {
            float v = acc[0][i] + acc[1][i];
            #pragma unroll
            for (int off = 32; off > 0; off >>= 1)
                v += __shfl_down(v, off, 64);
            if (lane == 0) atomicAdd(&seg_out[su * H + wc0 + i], v);
        }
    } else {
        int gr0 = base + r0;
        int s0 = -1, s1 = -1;
        if (gr0 < N) {
            s0 = find_seg(idx, B, gr0);
            if (gr0 + 1 < N) {
                s1 = s0;
                while (idx[2 * s1 + 1] <= gr0 + 1) ++s1;
            }
        }
        #pragma unroll
        for (int i = 0; i < CPW; ++i) {
            if (s0 >= 0) {
                if (s1 == s0) {
                    atomicAdd(&seg_out[s0 * H + wc0 + i], acc[0][i] + acc[1][i]);
                } else {
                    atomicAdd(&seg_out[s0 * H + wc0 + i], acc[0][i]);
                    if (s1 >= 0) atomicAdd(&seg_out[s1 * H + wc0 + i], acc[1][i]);
                }
            }
        }
    }
}

// ---------------------------------------------------------------------------
// final 2-layer MLP on [B,128] for P and Q + loss. One wave per segment b.
// ---------------------------------------------------------------------------
__global__ __launch_bounds__(64)
void final_loss_kernel(const float* __restrict__ P_sum, const float* __restrict__ Q_sum,
                       const float* __restrict__ fW, const float* __restrict__ fb,
                       const float* __restrict__ dists, float* __restrict__ out, int B)
{
    __shared__ float bufA[2][H];
    __shared__ float bufB[2][H];
    const int b = blockIdx.x;
    const int lane = threadIdx.x;

    bufA[0][lane]      = P_sum[b * H + lane];
    bufA[0][lane + 64] = P_sum[b * H + lane + 64];
    bufA[1][lane]      = Q_sum[b * H + lane];
    bufA[1][lane + 64] = Q_sum[b * H + lane + 64];
    __syncthreads();

    float* src = &bufA[0][0];
    float* dst = &bufB[0][0];
    for (int l = 0; l < NFIN; ++l) {
        for (int pq = 0; pq < 2; ++pq) {
            for (int half = 0; half < 2; ++half) {
                int c = lane + half * 64;
                float acc = fb[l * H + c];
                const float4* wr = (const float4*)(fW + l * H * H + c * H);
                #pragma unroll 4
                for (int k4 = 0; k4 < H / 4; ++k4) {
                    float4 w = wr[k4];
                    acc += w.x * src[pq * H + k4 * 4 + 0];
                    acc += w.y * src[pq * H + k4 * 4 + 1];
                    acc += w.z * src[pq * H + k4 * 4 + 2];
                    acc += w.w * src[pq * H + k4 * 4 + 3];
                }
                dst[pq * H + c] = fmaxf(acc, 0.f);
            }
        }
        __syncthreads();
        float* t = src; src = dst; dst = t;
    }
    // result now in src
    const float inv = 1.0f / (float)H;
    float part = 0.f;
    #pragma unroll
    for (int half = 0; half < 2; ++half) {
        int c = lane + half * 64;
        part += fabsf(src[0 * H + c] - src[1 * H + c]);
    }
    part *= inv;
    #pragma unroll
    for (int off = 32; off > 0; off >>= 1) part += __shfl_down(part, off, 64);
    if (lane == 0) {
        float d_pred = part * part;
        float dist = dists[b];
        float rel = (d_pred - dist) / dist;
        float term = rel * rel + fmaxf(dist - d_pred, 0.f);
        atomicAdd(out, term / (float)B);
    }
}

// ---------------------------------------------------------------------------
extern "C" void kernel_launch(void* const* d_in, const int* in_sizes, int n_in,
                              void* d_out, int out_size, void* d_ws, size_t ws_size,
                              hipStream_t stream)
{
    const float* Pblock = (const float*)d_in[0];
    const float* Qblock = (const float*)d_in[1];
    const int*   PidxRaw= (const int*)d_in[2];
    const int*   QidxRaw= (const int*)d_in[3];
    const float* dists  = (const float*)d_in[4];
    const float* hW0    = (const float*)d_in[5];
    const float* hb0    = (const float*)d_in[6];
    const float* hW     = (const float*)d_in[7];
    const float* hb     = (const float*)d_in[8];
    const float* fW     = (const float*)d_in[9];
    const float* fb     = (const float*)d_in[10];
    float*       out    = (float*)d_out;

    const int NP = in_sizes[0] / H_IN;
    const int NQ = in_sizes[1] / H_IN;
    const int B  = in_sizes[4];

    float* ws    = (float*)d_ws;
    float* P_sum = ws;                            // B*H floats
    float* Q_sum = ws + (size_t)B * H;            // B*H floats
    float* w0t   = ws + (size_t)2 * B * H;        // H_IN*H floats
    float* hWt   = w0t + H_IN * H;                // NHID*H*H floats
    int*   Pidx  = (int*)(hWt + NHID * H * H);    // B*2 ints
    int*   Qidx  = Pidx + 2 * B;                  // B*2 ints

    // zero the accumulation buffers (harness poisons ws/out with 0xAA)
    (void)hipMemsetAsync(P_sum, 0, (size_t)2 * B * H * sizeof(float), stream);
    (void)hipMemsetAsync(d_out, 0, sizeof(float), stream);

    normalize_idx<<<(2 * B + 255) / 256, 256, 0, stream>>>(PidxRaw, QidxRaw, Pidx, Qidx, 2 * B);

    const int n0 = H_IN * H;
    const int nh = NHID * H * H;
    const int nt = n0 + nh;
    transpose_weights<<<(nt + 255) / 256, 256, 0, stream>>>(hW0, hW, w0t, hWt, n0, nh);

    const int gp = (NP + TILE - 1) / TILE;
    const int gq = (NQ + TILE - 1) / TILE;
    mlp_seg_kernel<<<gp, NTHREADS, 0, stream>>>(Pblock, Pidx, B, w0t, hb0, hWt, hb, P_sum, NP);
    mlp_seg_kernel<<<gq, NTHREADS, 0, stream>>>(Qblock, Qidx, B, w0t, hb0, hWt, hb, Q_sum, NQ);

    final_loss_kernel<<<B, 64, 0, stream>>>(P_sum, Q_sum, fW, fb, dists, out, B);
}

// Round 13
// 1136.616 us; speedup vs baseline: 2.6383x; 2.6383x over previous
//
#include <hip/hip_runtime.h>
#include <hip/hip_bf16.h>

#define H 128
#define H_IN 3
#define ROWS 64
#define NTHREADS 512
#define NHID 9
#define NFIN 2

typedef unsigned short u16;
typedef short s16x8 __attribute__((ext_vector_type(8)));
typedef float f32x4 __attribute__((ext_vector_type(4)));

// bf16 round-to-nearest-even via bit ops
__device__ __forceinline__ u16 bf_rne(float x){
    unsigned u = __float_as_uint(x);
    unsigned r = (u + 0x7FFFu + ((u >> 16) & 1u)) >> 16;
    return (u16)r;
}
__device__ __forceinline__ float bf_f(u16 h){ return __uint_as_float(((unsigned)h) << 16); }

// ---------------------------------------------------------------------------
// Segment index normalization (int32 vs int64 shipping convention), as validated.
// ---------------------------------------------------------------------------
__global__ void normalize_idx(const int* __restrict__ rawP, const int* __restrict__ rawQ,
                              int* __restrict__ outP, int* __restrict__ outQ, int n) {
    int i = blockIdx.x * blockDim.x + threadIdx.x;
    if (i < n) {
        bool p64 = (rawP[1] == 0);
        bool q64 = (rawQ[1] == 0);
        outP[i] = p64 ? rawP[2 * i] : rawP[i];
        outQ[i] = q64 ? rawQ[2 * i] : rawQ[i];
    }
}

__device__ __forceinline__ int find_seg(const int* __restrict__ idx, int B, int r) {
    int lo = 0, hi = B - 1;
    while (lo < hi) {
        int mid = (lo + hi + 1) >> 1;
        if (idx[2 * mid] <= r) lo = mid; else hi = mid - 1;
    }
    return lo;
}

// ---------------------------------------------------------------------------
// Pack hidden weights into MFMA A-fragment order, split into bf16 hi/lo planes.
// A[m][k] = hW[ly][c = ct*16 + m][k]; frag elem (lane,j): m=lane&15, k=kt*32+(lane>>4)*8+j.
// pk[( (ly*8+ct)*4 + kt )*512 + lane*8 + j]
// ---------------------------------------------------------------------------
__global__ void pack_weights(const float* __restrict__ hW,
                             u16* __restrict__ pkhi, u16* __restrict__ pklo) {
    int i = blockIdx.x * blockDim.x + threadIdx.x;
    if (i >= NHID * 8 * 4 * 64 * 8) return;
    int j  = i & 7;
    int l6 = (i >> 3) & 63;
    int kt = (i >> 9) & 3;
    int ct = (i >> 11) & 7;
    int ly = i >> 14;
    int c = ct * 16 + (l6 & 15);
    int k = kt * 32 + (l6 >> 4) * 8 + j;
    float v = hW[ly * H * H + c * H + k];
    u16 hi = bf_rne(v);
    u16 lo = bf_rne(v - bf_f(hi));
    pkhi[i] = hi; pklo[i] = lo;
}

// ---------------------------------------------------------------------------
// Fused 10-layer MLP (hidden layers on MFMA, bf16 hi/lo split) + segment sum.
// Block = 64 rows, 8 waves; wave w owns cols [w*16, w*16+16).
// Per layer: Y^T tile = mfma(A=W-frag(regs), B=X^T-frag(LDS)), acc fp32.
// X planes in LDS row-major [row][k] bf16, XOR-swizzled: byte ^= (row&7)<<4.
// D-layout (m89): lane holds Y[r = nt*16+(lane&15)][c = w*16+(lane>>4)*4+reg].
// ---------------------------------------------------------------------------
__global__ __launch_bounds__(NTHREADS, 4)
void mlp_mfma_kernel(const float* __restrict__ X, const int* __restrict__ idx, int B,
                     const float* __restrict__ hW0, const float* __restrict__ hb0,
                     const u16* __restrict__ pkhi, const u16* __restrict__ pklo,
                     const float* __restrict__ hb,
                     float* __restrict__ seg_out, int N)
{
    __shared__ u16 lds[2][2][ROWS * H];   // [dbuf][hi/lo][row*128+k], 64 KB
    __shared__ int s_uni;

    const int tid  = threadIdx.x;
    const int lane = tid & 63;
    const int w    = tid >> 6;            // wave id = col-tile
    const int l15  = lane & 15;
    const int lhi  = lane >> 4;
    const int base = blockIdx.x * ROWS;
    const int c0   = (w << 4) + (lhi << 2);   // this lane's 4 output cols

    if (tid == 0) {
        int last = base + ROWS - 1;
        if (last >= N) s_uni = -1;
        else {
            int sa = find_seg(idx, B, base);
            int sb = find_seg(idx, B, last);
            s_uni = (sa == sb) ? sa : -1;
        }
    }

    // ---- layer 0 (K=3, fp32 VALU), write bf16 hi/lo planes into buf 0 ----
    {
        float4 b0 = *(const float4*)&hb0[c0];
        float w0[4][3];
        #pragma unroll
        for (int rg = 0; rg < 4; ++rg)
            #pragma unroll
            for (int k = 0; k < 3; ++k)
                w0[rg][k] = hW0[(c0 + rg) * 3 + k];
        float bb[4] = {b0.x, b0.y, b0.z, b0.w};
        #pragma unroll
        for (int nt = 0; nt < 4; ++nt) {
            int r = base + nt * 16 + l15;
            float x0 = 0.f, x1 = 0.f, x2 = 0.f;
            if (r < N) { const float* xp = &X[(size_t)r * 3]; x0 = xp[0]; x1 = xp[1]; x2 = xp[2]; }
            u16 hi[4], lo[4];
            #pragma unroll
            for (int rg = 0; rg < 4; ++rg) {
                float y = fmaf(x0, w0[rg][0], fmaf(x1, w0[rg][1], fmaf(x2, w0[rg][2], bb[rg])));
                y = fmaxf(y, 0.f);
                hi[rg] = bf_rne(y);
                lo[rg] = bf_rne(y - bf_f(hi[rg]));
            }
            int row  = nt * 16 + l15;
            int boff = (w << 5) + (lhi << 3);            // c0*2 bytes
            int a = row * 256 + (boff ^ ((row & 7) << 4));
            *(ushort4*)((char*)&lds[0][0][0] + a) = make_ushort4(hi[0], hi[1], hi[2], hi[3]);
            *(ushort4*)((char*)&lds[0][1][0] + a) = make_ushort4(lo[0], lo[1], lo[2], lo[3]);
        }
    }

    // ---- 9 hidden layers on MFMA ----
    int cur = 0;
    f32x4 acc[4];
    for (int ly = 0; ly < NHID; ++ly) {
        float4 bias = *(const float4*)&hb[ly * H + c0];
        #pragma unroll
        for (int nt = 0; nt < 4; ++nt) { acc[nt][0] = bias.x; acc[nt][1] = bias.y; acc[nt][2] = bias.z; acc[nt][3] = bias.w; }

        const u16* ph = pkhi + (((ly * 8 + w) * 4) << 9) + (lane << 3);
        const u16* pl = pklo + (((ly * 8 + w) * 4) << 9) + (lane << 3);
        s16x8 wh[4], wl[4];
        #pragma unroll
        for (int kt = 0; kt < 4; ++kt) {
            wh[kt] = *(const s16x8*)(ph + (kt << 9));
            wl[kt] = *(const s16x8*)(pl + (kt << 9));
        }

        __syncthreads();   // prev stage's writes to lds[cur] visible; prev reads drained

        #pragma unroll
        for (int nt = 0; nt < 4; ++nt) {
            int row   = nt * 16 + l15;
            int rbase = row * 256;
            int sw    = (row & 7) << 4;
            #pragma unroll
            for (int kt = 0; kt < 4; ++kt) {
                int a = rbase + (((kt << 6) + (lhi << 4)) ^ sw);
                s16x8 xh = *(const s16x8*)((const char*)&lds[cur][0][0] + a);
                s16x8 xl = *(const s16x8*)((const char*)&lds[cur][1][0] + a);
                acc[nt] = __builtin_amdgcn_mfma_f32_16x16x32_bf16(wh[kt], xh, acc[nt], 0, 0, 0);
                acc[nt] = __builtin_amdgcn_mfma_f32_16x16x32_bf16(wl[kt], xh, acc[nt], 0, 0, 0);
                acc[nt] = __builtin_amdgcn_mfma_f32_16x16x32_bf16(wh[kt], xl, acc[nt], 0, 0, 0);
            }
        }

        if (ly < NHID - 1) {
            int nxt = cur ^ 1;
            #pragma unroll
            for (int nt = 0; nt < 4; ++nt) {
                u16 hi[4], lo[4];
                #pragma unroll
                for (int rg = 0; rg < 4; ++rg) {
                    float y = fmaxf(acc[nt][rg], 0.f);
                    hi[rg] = bf_rne(y);
                    lo[rg] = bf_rne(y - bf_f(hi[rg]));
                }
                int row  = nt * 16 + l15;
                int boff = (w << 5) + (lhi << 3);
                int a = row * 256 + (boff ^ ((row & 7) << 4));
                *(ushort4*)((char*)&lds[nxt][0][0] + a) = make_ushort4(hi[0], hi[1], hi[2], hi[3]);
                *(ushort4*)((char*)&lds[nxt][1][0] + a) = make_ushort4(lo[0], lo[1], lo[2], lo[3]);
            }
            cur = nxt;
        } else {
            #pragma unroll
            for (int nt = 0; nt < 4; ++nt)
                #pragma unroll
                for (int rg = 0; rg < 4; ++rg)
                    acc[nt][rg] = fmaxf(acc[nt][rg], 0.f);
        }
    }

    // ---- fused segment sum ----
    // lane holds Y[r = base+nt*16+l15][c = c0+rg]; 16-lane subgroup (same lhi) shares cols.
    if (s_uni >= 0) {
        f32x4 v;
        #pragma unroll
        for (int rg = 0; rg < 4; ++rg) v[rg] = acc[0][rg] + acc[1][rg] + acc[2][rg] + acc[3][rg];
        #pragma unroll
        for (int m = 1; m < 16; m <<= 1)
            #pragma unroll
            for (int rg = 0; rg < 4; ++rg) v[rg] += __shfl_xor(v[rg], m, 64);
        if (l15 == 0) {
            #pragma unroll
            for (int rg = 0; rg < 4; ++rg) atomicAdd(&seg_out[s_uni * H + c0 + rg], v[rg]);
        }
    } else {
        #pragma unroll
        for (int nt = 0; nt < 4; ++nt) {
            int r = base + nt * 16 + l15;
            int s = (r < N) ? find_seg(idx, B, r) : -1;
            int smin = s, smax = s;
            #pragma unroll
            for (int m = 1; m < 16; m <<= 1) {
                smin = min(smin, __shfl_xor(smin, m, 64));
                smax = max(smax, __shfl_xor(smax, m, 64));
            }
            if (smin == smax && smin >= 0) {
                f32x4 v = acc[nt];
                #pragma unroll
                for (int m = 1; m < 16; m <<= 1)
                    #pragma unroll
                    for (int rg = 0; rg < 4; ++rg) v[rg] += __shfl_xor(v[rg], m, 64);
                if (l15 == 0)
                    for (int rg = 0; rg < 4; ++rg) atomicAdd(&seg_out[smin * H + c0 + rg], v[rg]);
            } else if (s >= 0) {
                #pragma unroll
                for (int rg = 0; rg < 4; ++rg) atomicAdd(&seg_out[s * H + c0 + rg], acc[nt][rg]);
            }
        }
    }
}

// ---------------------------------------------------------------------------
// final 2-layer MLP on [B,128] for P and Q + loss (validated round 11; unchanged)
// ---------------------------------------------------------------------------
__global__ __launch_bounds__(64)
void final_loss_kernel(const float* __restrict__ P_sum, const float* __restrict__ Q_sum,
                       const float* __restrict__ fW, const float* __restrict__ fb,
                       const float* __restrict__ dists, float* __restrict__ out, int B)
{
    __shared__ float bufA[2][H];
    __shared__ float bufB[2][H];
    const int b = blockIdx.x;
    const int lane = threadIdx.x;

    bufA[0][lane]      = P_sum[b * H + lane];
    bufA[0][lane + 64] = P_sum[b * H + lane + 64];
    bufA[1][lane]      = Q_sum[b * H + lane];
    bufA[1][lane + 64] = Q_sum[b * H + lane + 64];
    __syncthreads();

    float* src = &bufA[0][0];
    float* dst = &bufB[0][0];
    for (int l = 0; l < NFIN; ++l) {
        for (int pq = 0; pq < 2; ++pq) {
            for (int half = 0; half < 2; ++half) {
                int c = lane + half * 64;
                float acc = fb[l * H + c];
                const float4* wr = (const float4*)(fW + l * H * H + c * H);
                #pragma unroll 4
                for (int k4 = 0; k4 < H / 4; ++k4) {
                    float4 wv = wr[k4];
                    acc += wv.x * src[pq * H + k4 * 4 + 0];
                    acc += wv.y * src[pq * H + k4 * 4 + 1];
                    acc += wv.z * src[pq * H + k4 * 4 + 2];
                    acc += wv.w * src[pq * H + k4 * 4 + 3];
                }
                dst[pq * H + c] = fmaxf(acc, 0.f);
            }
        }
        __syncthreads();
        float* t = src; src = dst; dst = t;
    }
    const float inv = 1.0f / (float)H;
    float part = 0.f;
    #pragma unroll
    for (int half = 0; half < 2; ++half) {
        int c = lane + half * 64;
        part += fabsf(src[0 * H + c] - src[1 * H + c]);
    }
    part *= inv;
    #pragma unroll
    for (int off = 32; off > 0; off >>= 1) part += __shfl_down(part, off, 64);
    if (lane == 0) {
        float d_pred = part * part;
        float dist = dists[b];
        float rel = (d_pred - dist) / dist;
        float term = rel * rel + fmaxf(dist - d_pred, 0.f);
        atomicAdd(out, term / (float)B);
    }
}

// ---------------------------------------------------------------------------
extern "C" void kernel_launch(void* const* d_in, const int* in_sizes, int n_in,
                              void* d_out, int out_size, void* d_ws, size_t ws_size,
                              hipStream_t stream)
{
    const float* Pblock  = (const float*)d_in[0];
    const float* Qblock  = (const float*)d_in[1];
    const int*   PidxRaw = (const int*)d_in[2];
    const int*   QidxRaw = (const int*)d_in[3];
    const float* dists   = (const float*)d_in[4];
    const float* hW0     = (const float*)d_in[5];
    const float* hb0     = (const float*)d_in[6];
    const float* hW      = (const float*)d_in[7];
    const float* hb      = (const float*)d_in[8];
    const float* fW      = (const float*)d_in[9];
    const float* fb      = (const float*)d_in[10];
    float*       out     = (float*)d_out;

    const int NP = in_sizes[0] / H_IN;
    const int NQ = in_sizes[1] / H_IN;
    const int B  = in_sizes[4];

    float* ws    = (float*)d_ws;
    float* P_sum = ws;                              // B*H floats
    float* Q_sum = ws + (size_t)B * H;              // B*H floats
    char*  p     = (char*)(ws + (size_t)2 * B * H);
    int* Pidx = (int*)p;               p += (size_t)2 * B * sizeof(int);
    int* Qidx = (int*)p;               p += (size_t)2 * B * sizeof(int);
    u16* pkhi = (u16*)p;               p += (size_t)NHID * 16384 * sizeof(u16);
    u16* pklo = (u16*)p;

    (void)hipMemsetAsync(P_sum, 0, (size_t)2 * B * H * sizeof(float), stream);
    (void)hipMemsetAsync(d_out, 0, sizeof(float), stream);

    normalize_idx<<<(2 * B + 255) / 256, 256, 0, stream>>>(PidxRaw, QidxRaw, Pidx, Qidx, 2 * B);
    pack_weights<<<(NHID * 16384 + 255) / 256, 256, 0, stream>>>(hW, pkhi, pklo);

    const int gp = (NP + ROWS - 1) / ROWS;
    const int gq = (NQ + ROWS - 1) / ROWS;
    mlp_mfma_kernel<<<gp, NTHREADS, 0, stream>>>(Pblock, Pidx, B, hW0, hb0, pkhi, pklo, hb, P_sum, NP);
    mlp_mfma_kernel<<<gq, NTHREADS, 0, stream>>>(Qblock, Qidx, B, hW0, hb0, pkhi, pklo, hb, Q_sum, NQ);

    final_loss_kernel<<<B, 64, 0, stream>>>(P_sum, Q_sum, fW, fb, dists, out, B);
}